// Round 14
// baseline (325.619 us; speedup 1.0000x reference)
//
#include <hip/hip_runtime.h>
#include <hip/hip_fp16.h>
#include <math.h>

// Problem constants
#define NN 100000
#define EE 1600000
constexpr int IN_F = 256, HID = 128, OUT_F = 64;

// CSR bucket-sort geometry
#define NB 196
#define CAP 16384
#define CH 4096
#define NCHUNK 391

typedef __bf16    bf16x8 __attribute__((ext_vector_type(8)));
typedef _Float16  h16x8  __attribute__((ext_vector_type(8)));
typedef float     f32x4  __attribute__((ext_vector_type(4)));

__device__ __forceinline__ f32x4 mfma16b(bf16x8 a, bf16x8 b, f32x4 c){
  return __builtin_amdgcn_mfma_f32_16x16x32_bf16(a, b, c, 0, 0, 0);
}
__device__ __forceinline__ f32x4 mfma16h(h16x8 a, h16x8 b, f32x4 c){
  return __builtin_amdgcn_mfma_f32_16x16x32_f16(a, b, c, 0, 0, 0);
}

// f16 (lo/hi of g2) * f32 alpha + f32 acc (VOP3P mix, exact f32 accumulate)
__device__ __forceinline__ void fmamix2(float& aLo, float& aHi, __half2 g2, float al){
  asm("v_fma_mix_f32 %0, %2, %3, %0 op_sel:[0,0,0] op_sel_hi:[1,0,0]\n\t"
      "v_fma_mix_f32 %1, %2, %3, %1 op_sel:[1,0,0] op_sel_hi:[1,0,0]"
      : "+v"(aLo), "+v"(aHi) : "v"(g2), "v"(al));
}

__device__ __forceinline__ float wred_max(float v){
#pragma unroll
  for (int m=1; m<64; m<<=1) v = fmaxf(v, __shfl_xor(v, m, 64));
  return v;
}
__device__ __forceinline__ float wred_sum(float v){
#pragma unroll
  for (int m=1; m<64; m<<=1) v += __shfl_xor(v, m, 64);
  return v;
}

__device__ __forceinline__ unsigned fkey(float x){
  unsigned u = __float_as_uint(x);
  return (u & 0x80000000u) ? ~u : (u ^ 0x80000000u);
}
__device__ __forceinline__ float funkey(unsigned k){
  return __uint_as_float((k & 0x80000000u) ? (k ^ 0x80000000u) : ~k);
}

// ---------------- CSR build, pass 1 (single dst read: staged in registers) ----------------
__global__ __launch_bounds__(256) void k_bin(const int* __restrict__ src,
    const int* __restrict__ dst, int* __restrict__ bucketCnt, int* __restrict__ recs)
{
  __shared__ int cnt[NB];
  __shared__ int base[NB];
  const int tid = threadIdx.x;
  const int e0 = blockIdx.x * CH;
  const int ne = min(CH, EE - e0);

  for (int i=tid; i<NB; i+=256) cnt[i] = 0;
  __syncthreads();
  int d[16];
#pragma unroll
  for (int q=0; q<16; q++){
    int i = tid + q*256;
    d[q] = (i < ne) ? dst[e0+i] : -1;
    if (d[q] >= 0) atomicAdd(&cnt[d[q]>>9], 1);
  }
  __syncthreads();
  for (int i=tid; i<NB; i+=256) base[i] = atomicAdd(&bucketCnt[i], cnt[i]);
  __syncthreads();
  for (int i=tid; i<NB; i+=256) cnt[i] = 0;
  __syncthreads();
#pragma unroll
  for (int q=0; q<16; q++){
    int i = tid + q*256;
    if (d[q] >= 0){
      int b = d[q] >> 9;
      int r = atomicAdd(&cnt[b], 1);
      int pos = base[b] + r;
      if (pos < CAP) recs[(size_t)b*CAP + pos] = src[e0+i] | ((d[q] & 511) << 17);
    }
  }
}

// ---------------- CSR build, pass 2 (inline bucket prefix) ----------------
__global__ __launch_bounds__(512) void k_csr(const int* __restrict__ recs,
    const int* __restrict__ bucketCnt, int* __restrict__ rp, int* __restrict__ colsrc)
{
  __shared__ int scnt[NB];
  __shared__ int hist[513];
  __shared__ int srcbuf[CAP];
  __shared__ int bs_sh;
  const int tid = threadIdx.x;
  const int b = blockIdx.x;
  for (int i=tid; i<NB; i+=512) scnt[i] = min(bucketCnt[i], CAP);
  if (tid < 513) hist[tid] = 0;
  if (tid == 0) hist[512] = 0;
  __syncthreads();
  if (tid == 0){
    int acc = 0;
    for (int i=0; i<b; i++) acc += scnt[i];
    bs_sh = acc;
  }
  __syncthreads();
  const int bstart = bs_sh;
  const int cntb = scnt[b];
  const int n0 = b << 9;
  const int nnode = min(512, NN - n0);
  const int* rb = recs + (size_t)b*CAP;

  for (int i=tid; i<cntb; i+=512) atomicAdd(&hist[(rb[i] >> 17) + 1], 1);
  __syncthreads();
#pragma unroll
  for (int off=1; off<513; off<<=1){
    int v0 = (tid >= off) ? hist[tid-off] : 0;
    int i1 = tid + 512;
    int v1 = (i1 < 513 && i1 >= off) ? hist[i1-off] : 0;
    __syncthreads();
    hist[tid] += v0;
    if (i1 < 513) hist[i1] += v1;
    __syncthreads();
  }
  for (int l=tid; l<nnode; l+=512) rp[n0+l] = bstart + hist[l];
  if (b == 0 && tid == 0) rp[NN] = EE;
  __syncthreads();
  for (int i=tid; i<cntb; i+=512){
    int rec = rb[i];
    int r = atomicAdd(&hist[rec >> 17], 1);
    srcbuf[r] = rec & 0x1FFFF;
  }
  __syncthreads();
  for (int i=tid; i<cntb; i+=512) colsrc[bstart + i] = srcbuf[i];
}

// ---------------- fused weight pre-split + misc zeroing (one launch) ----------------
__global__ void k_wsplit_all(
    const float* __restrict__ W_in, __bf16* __restrict__ whiI, __bf16* __restrict__ wloI,
    const float* __restrict__ W1, _Float16* __restrict__ w1h, _Float16* __restrict__ w1l,
    const float* __restrict__ W2, _Float16* __restrict__ w2h, _Float16* __restrict__ w2l,
    const float* __restrict__ W_out, _Float16* __restrict__ wOh, _Float16* __restrict__ wOl,
    int* __restrict__ misc)
{
  int idx = blockIdx.x*256 + threadIdx.x;
  if (idx < NB+2) misc[idx] = 0;             // bucketCnt | gk1 | gk2
  if (idx < 32768){                          // W_in [256][128]
    int k = idx >> 7, n = idx & 127;
    float v = W_in[idx];
    __bf16 h = (__bf16)v;
    whiI[n*256 + k] = h;
    wloI[n*256 + k] = (__bf16)(v - (float)h);
  } else if (idx < 49152){                   // W1 [128][128]
    int i = idx - 32768, k = i >> 7, n = i & 127;
    float v = W1[i] * 16.f;
    _Float16 h = (_Float16)v;
    w1h[n*128 + k] = h;
    w1l[n*128 + k] = (_Float16)(v - (float)h);
  } else if (idx < 65536){                   // W2 [128][128]
    int i = idx - 49152, k = i >> 7, n = i & 127;
    float v = W2[i] * 16.f;
    _Float16 h = (_Float16)v;
    w2h[n*128 + k] = h;
    w2l[n*128 + k] = (_Float16)(v - (float)h);
  } else if (idx < 73728){                   // W_out [128][64]
    int i = idx - 65536, k = i / 64, n = i - k*64;
    float v = W_out[i] * 16.f;
    _Float16 h = (_Float16)v;
    wOh[n*128 + k] = h;
    wOl[n*128 + k] = (_Float16)(v - (float)h);
  }
}

// ---------------- GEMM1: H = x @ W_in + b_in  (f32 A -> bf16 split; fp16 out) ----------------
// 128-row tiles (782 blocks = 3.05/CU, balanced); wave owns 32 rows; acc[2][8]=64 VGPR.
// (256,3) cap ~170 VGPR: est. use ~150 — watch for spill (r11 symptom: WRITE blowup).
__global__ __launch_bounds__(256, 3) void k_gemm_in(
    const float* __restrict__ A, const __bf16* __restrict__ Bhi, const __bf16* __restrict__ Blo,
    const float* __restrict__ bias, __half* __restrict__ C, int nrows)
{
  constexpr int K = 256, BN = 128, NF = 8;
  __shared__ __bf16 Ah[128][36];   // 72B stride (known-good)
  __shared__ __bf16 Al[128][36];
  __shared__ __bf16 Bh[BN][36];
  __shared__ __bf16 Bl[BN][36];
  const int tid = threadIdx.x, w = tid >> 6, lane = tid & 63;
  const int lr = lane & 15, lk = (lane >> 4) * 8;
  const int rowBase = blockIdx.x * 128;

  f32x4 acc[2][NF];
#pragma unroll
  for (int f=0; f<2; f++)
#pragma unroll
    for (int nf=0; nf<NF; nf++) acc[f][nf] = (f32x4)(0.f);

  const int bn = tid >> 1, bo = (tid & 1) * 16;

  for (int kc=0; kc<K; kc+=32){
    // A: 128 rows x 32 f32 = 1024 pieces of 16B; 4/thread; 8 lanes = 128B line
    float4 av[4];
#pragma unroll
    for (int k8=0; k8<4; k8++){
      int P = tid + 256*k8;
      int r = P >> 3, pc = P & 7;
      int gr = rowBase + r; if (gr >= nrows) gr = nrows - 1;
      av[k8] = *(const float4*)(A + (size_t)gr*K + kc + pc*4);
    }
    bf16x8 bh0, bh1, bl0, bl1;
    {
      const __bf16* ph = Bhi + (size_t)bn*K + kc + bo;
      const __bf16* pl = Blo + (size_t)bn*K + kc + bo;
      bh0 = *(const bf16x8*)(ph);  bh1 = *(const bf16x8*)(ph + 8);
      bl0 = *(const bf16x8*)(pl);  bl1 = *(const bf16x8*)(pl + 8);
    }
    __syncthreads();
#pragma unroll
    for (int k8=0; k8<4; k8++){
      int P = tid + 256*k8;
      int r = P >> 3, pc = P & 7;
      float fv[4] = {av[k8].x, av[k8].y, av[k8].z, av[k8].w};
      __bf16 h4[4], l4[4];
#pragma unroll
      for (int u=0; u<4; u++){
        __bf16 h = (__bf16)fv[u];
        h4[u] = h; l4[u] = (__bf16)(fv[u] - (float)h);
      }
      *(uint2*)&Ah[r][pc*4] = *(uint2*)h4;
      *(uint2*)&Al[r][pc*4] = *(uint2*)l4;
    }
    *(bf16x8*)&Bh[bn][bo]     = bh0;  *(bf16x8*)&Bh[bn][bo + 8] = bh1;
    *(bf16x8*)&Bl[bn][bo]     = bl0;  *(bf16x8*)&Bl[bn][bo + 8] = bl1;
    __syncthreads();

    bf16x8 fah[2], fal[2];
#pragma unroll
    for (int f=0; f<2; f++){
      fah[f] = *(const bf16x8*)&Ah[w*32 + f*16 + lr][lk];
      fal[f] = *(const bf16x8*)&Al[w*32 + f*16 + lr][lk];
    }
#pragma unroll
    for (int nf=0; nf<NF; nf++){
      bf16x8 bh = *(const bf16x8*)&Bh[nf*16 + lr][lk];
#pragma unroll
      for (int f=0; f<2; f++) acc[f][nf] = mfma16b(fah[f], bh, acc[f][nf]);
#pragma unroll
      for (int f=0; f<2; f++) acc[f][nf] = mfma16b(fal[f], bh, acc[f][nf]);
      bf16x8 bl = *(const bf16x8*)&Bl[nf*16 + lr][lk];
#pragma unroll
      for (int f=0; f<2; f++) acc[f][nf] = mfma16b(fah[f], bl, acc[f][nf]);
    }
  }

  const int rq = lane >> 4;
#pragma unroll
  for (int f=0; f<2; f++){
    const int rbase = rowBase + w*32 + f*16 + rq*4;
#pragma unroll
    for (int i=0; i<4; i++){
      int row = rbase + i;
      if (row < nrows){
#pragma unroll
        for (int nf=0; nf<NF; nf++){
          float v = acc[f][nf][i] + bias[nf*16 + lr];
          C[(size_t)row*BN + nf*16 + lr] = __float2half(v);
        }
      }
    }
  }
}

// ---------------- f16 GEMM, BK=32, 128-row tiles ----------------
// acc[2][NF] (<=64 VGPR); (256,3) cap ~170 — est. use ~130.
template<int K, int BN, bool ATT, bool BIAS, int OMODE>
__global__ __launch_bounds__(256, 3) void k_gemm_f16(
    const _Float16* __restrict__ A, const _Float16* __restrict__ Whi,
    const _Float16* __restrict__ Wlo, const float* __restrict__ bias,
    void* __restrict__ C0, const float* __restrict__ attS, const float* __restrict__ attD,
    float* __restrict__ asrc, float* __restrict__ adst,
    unsigned* __restrict__ gk, int nrows)
{
  constexpr int NF = BN/16;
  __shared__ _Float16 Ah[128][40];   // 80B stride: <=2-way (free)
  __shared__ _Float16 Bh[BN][40];
  __shared__ _Float16 Bl[BN][40];
  const int tid = threadIdx.x, w = tid >> 6, lane = tid & 63;
  const int lr = lane & 15, lk = (lane >> 4) * 8;
  const int rowBase = blockIdx.x * 128;

  f32x4 acc[2][NF];
#pragma unroll
  for (int f=0; f<2; f++)
#pragma unroll
    for (int nf=0; nf<NF; nf++) acc[f][nf] = (f32x4)(0.f);

  const bool bact = tid < BN*2;
  const int bn = tid >> 1, bo = (tid & 1) * 16;

  for (int kc=0; kc<K; kc+=32){
    // A: 128 rows x 32 f16 = 512 pieces of 16B; 2/thread
    h16x8 av[2];
#pragma unroll
    for (int k4=0; k4<2; k4++){
      int P = tid + 256*k4;
      int r = P >> 2, pc = P & 3;
      int gr = rowBase + r; if (gr >= nrows) gr = nrows - 1;
      av[k4] = *(const h16x8*)(A + (size_t)gr*K + kc + pc*8);
    }
    h16x8 bh0, bh1, bl0, bl1;
    if (bact){
      const _Float16* ph = Whi + (size_t)bn*K + kc + bo;
      const _Float16* pl = Wlo + (size_t)bn*K + kc + bo;
      bh0 = *(const h16x8*)(ph);  bh1 = *(const h16x8*)(ph + 8);
      bl0 = *(const h16x8*)(pl);  bl1 = *(const h16x8*)(pl + 8);
    }
    __syncthreads();
#pragma unroll
    for (int k4=0; k4<2; k4++){
      int P = tid + 256*k4;
      int r = P >> 2, pc = P & 3;
      *(h16x8*)&Ah[r][pc*8] = av[k4];
    }
    if (bact){
      *(h16x8*)&Bh[bn][bo]     = bh0;  *(h16x8*)&Bh[bn][bo + 8] = bh1;
      *(h16x8*)&Bl[bn][bo]     = bl0;  *(h16x8*)&Bl[bn][bo + 8] = bl1;
    }
    __syncthreads();

    h16x8 fah[2];
#pragma unroll
    for (int f=0; f<2; f++) fah[f] = *(const h16x8*)&Ah[w*32 + f*16 + lr][lk];
#pragma unroll
    for (int nf=0; nf<NF; nf++){
      h16x8 bh = *(const h16x8*)&Bh[nf*16 + lr][lk];
#pragma unroll
      for (int f=0; f<2; f++) acc[f][nf] = mfma16h(fah[f], bh, acc[f][nf]);
      h16x8 bl = *(const h16x8*)&Bl[nf*16 + lr][lk];
#pragma unroll
      for (int f=0; f<2; f++) acc[f][nf] = mfma16h(fah[f], bl, acc[f][nf]);
    }
  }
  // undo the x16 weight scale
#pragma unroll
  for (int f=0; f<2; f++)
#pragma unroll
    for (int nf=0; nf<NF; nf++) acc[f][nf] *= 0.0625f;

  const int rq = lane >> 4;
  float pmax = -3e38f;
#pragma unroll
  for (int f=0; f<2; f++){
    const int rbase = rowBase + w*32 + f*16 + rq*4;
    if (ATT){
      float ps[4] = {0.f,0.f,0.f,0.f}, pd[4] = {0.f,0.f,0.f,0.f};
#pragma unroll
      for (int nf=0; nf<NF; nf++){
        float sv = attS[nf*16 + lr], dv = attD[nf*16 + lr];
#pragma unroll
        for (int i=0;i<4;i++){
          ps[i] = fmaf(acc[f][nf][i], sv, ps[i]);
          pd[i] = fmaf(acc[f][nf][i], dv, pd[i]);
        }
      }
#pragma unroll
      for (int mm=1; mm<16; mm<<=1){
#pragma unroll
        for (int i=0;i<4;i++){
          ps[i] += __shfl_xor(ps[i], mm, 64);
          pd[i] += __shfl_xor(pd[i], mm, 64);
        }
      }
      if (lr == 0){
#pragma unroll
        for (int i=0;i<4;i++){
          int row = rbase + i;
          if (row < nrows){ asrc[row] = ps[i]; adst[row] = pd[i]; }
        }
        pmax = fmaxf(pmax, fmaxf(fmaxf(ps[0],ps[1]), fmaxf(ps[2],ps[3])));
      }
    }
#pragma unroll
    for (int i=0;i<4;i++){
      int row = rbase + i;
      if (row < nrows){
#pragma unroll
        for (int nf=0; nf<NF; nf++){
          float v = acc[f][nf][i] + (BIAS ? bias[nf*16 + lr] : 0.f);
          size_t cidx = (size_t)row*BN + nf*16 + lr;
          if constexpr (OMODE == 0) ((float*)C0)[cidx] = v;
          else                      ((__half*)C0)[cidx] = __float2half(v);
        }
      }
    }
  }
  if (ATT){
    pmax = wred_max(pmax);
    if (lane == 0) atomicMax(gk, fkey(pmax));
  }
}

// ---------------- fused GAT aggregation (unchanged from r13) ----------------
__global__ __launch_bounds__(512) void k_agg2(const __half* __restrict__ g,
    const float* __restrict__ asrc, const float* __restrict__ adst,
    const int* __restrict__ rp, const int* __restrict__ cs,
    const float* __restrict__ bias, const unsigned* __restrict__ gkey,
    __half* __restrict__ out)
{
  __shared__ int2 ebuf[8][128];
  int w = threadIdx.x >> 6, lane = threadIdx.x & 63;
  int node = blockIdx.x*8 + w;
  if (node >= NN) return;
  int r0 = rp[node], deg = rp[node+1] - r0;
  float ad = adst[node];
  float tC = funkey(*gkey) + ad;
  float C = (tC > 0.f) ? tC : 0.2f*tC;
  const int eg = lane >> 4, cl = lane & 15;
  const __half* gcl = g + cl*8;
  const int2* eb = &ebuf[w][eg];

  float ssum = 0.f;
  float a[8] = {0.f,0.f,0.f,0.f,0.f,0.f,0.f,0.f};

  for (int base = 0; base < deg; base += 128){
    int cnt = min(deg - base, 128);
    int cpad = (cnt + 3) & ~3;
    for (int i = lane; i < cpad; i += 64){
      int s = 0; float p = 0.f;
      if (i < cnt){
        s = cs[r0 + base + i];
        float t = asrc[s] + ad;
        float e = (t > 0.f) ? t : 0.2f*t;
        p = __expf(e - C);
        ssum += p;
      }
      ebuf[w][i] = make_int2(s, __float_as_int(p));
    }
    int nst = cpad >> 2;
    int2 e0 = eb[0];
    int2 e1 = (1 < nst) ? eb[4]  : make_int2(0,0);
    int2 e2 = (2 < nst) ? eb[8]  : make_int2(0,0);
    int2 e3 = (3 < nst) ? eb[12] : make_int2(0,0);
    float4 g0 = *(const float4*)(gcl + ((size_t)((unsigned)e0.x << 7)));
    float4 g1 = *(const float4*)(gcl + ((size_t)((unsigned)e1.x << 7)));
    float4 g2 = *(const float4*)(gcl + ((size_t)((unsigned)e2.x << 7)));
    float4 g3 = *(const float4*)(gcl + ((size_t)((unsigned)e3.x << 7)));

#define GSTEP2(EV, GV, SOFF)                                                 \
    {                                                                        \
      float al = __int_as_float(EV.y); float4 cur = GV;                      \
      int nj = j + 4 + SOFF;                                                 \
      if (nj < nst){                                                         \
        EV = eb[4*nj];                                                       \
        GV = *(const float4*)(gcl + ((size_t)((unsigned)EV.x << 7)));        \
      }                                                                      \
      const __half2* hp = (const __half2*)&cur;                              \
      fmamix2(a[0], a[1], hp[0], al);                                        \
      fmamix2(a[2], a[3], hp[1], al);                                        \
      fmamix2(a[4], a[5], hp[2], al);                                        \
      fmamix2(a[6], a[7], hp[3], al);                                        \
    }

    for (int j = 0; j < nst; j += 4){
      GSTEP2(e0, g0, 0)
      if (j + 1 < nst) GSTEP2(e1, g1, 1)
      if (j + 2 < nst) GSTEP2(e2, g2, 2)
      if (j + 3 < nst) GSTEP2(e3, g3, 3)
    }
#undef GSTEP2
  }

  ssum = wred_sum(ssum);
#pragma unroll
  for (int u=0; u<8; u++){
    a[u] += __shfl_xor(a[u], 16, 64);
    a[u] += __shfl_xor(a[u], 32, 64);
  }
  if (eg == 0){
    float inv = 1.f/(ssum + 1e-16f);
    __half hv[8];
#pragma unroll
    for (int u=0; u<8; u++)
      hv[u] = __float2half(fmaxf(a[u]*inv + bias[cl*8 + u], 0.f));
    *(float4*)(out + (size_t)node*HID + cl*8) = *(float4*)hv;
  }
}

// ---------------- host ----------------
extern "C" void kernel_launch(void* const* d_in, const int* in_sizes, int n_in,
                              void* d_out, int out_size, void* d_ws, size_t ws_size,
                              hipStream_t stream) {
  const float* x     = (const float*)d_in[0];
  const int*   ei    = (const int*)  d_in[1];
  const float* W_in  = (const float*)d_in[2];
  const float* b_in  = (const float*)d_in[3];
  const float* W1    = (const float*)d_in[4];
  const float* as1   = (const float*)d_in[5];
  const float* ad1   = (const float*)d_in[6];
  const float* bias1 = (const float*)d_in[7];
  const float* W2    = (const float*)d_in[8];
  const float* as2   = (const float*)d_in[9];
  const float* ad2   = (const float*)d_in[10];
  const float* bias2 = (const float*)d_in[11];
  const float* W_out = (const float*)d_in[12];
  const float* b_out = (const float*)d_in[13];
  float* out = (float*)d_out;

  char* ws = (char*)d_ws;
  size_t off = 0;
  auto alloc = [&](size_t bytes)->void*{ void* p = ws + off; off += (bytes + 255) & ~255ull; return p; };
  __half*   H    = (__half*)  alloc((size_t)NN*HID*2);   // h; later o2
  __half*   G    = (__half*)  alloc((size_t)NN*HID*2);   // g (both layers)
  __half*   O1   = (__half*)  alloc((size_t)NN*HID*2);   // o1
  float*    asrc = (float*)   alloc((size_t)NN*4);
  float*    adst = (float*)   alloc((size_t)NN*4);
  int*      rp   = (int*)     alloc((size_t)(NN+1)*4);
  int*      colsrc = (int*)   alloc((size_t)EE*4);
  int*      recs   = (int*)   alloc((size_t)NB*CAP*4);   // 12.85 MB
  int*      misc   = (int*)   alloc((size_t)(NB+2)*4);   // bucketCnt | gk1 | gk2
  int*      bucketCnt = misc;
  unsigned* gk1 = (unsigned*)(misc + NB);
  unsigned* gk2 = (unsigned*)(misc + NB + 1);
  __bf16*   whiI = (__bf16*) alloc((size_t)HID*IN_F*2);
  __bf16*   wloI = (__bf16*) alloc((size_t)HID*IN_F*2);
  _Float16* w1h  = (_Float16*)alloc((size_t)HID*HID*2);
  _Float16* w1l  = (_Float16*)alloc((size_t)HID*HID*2);
  _Float16* w2h  = (_Float16*)alloc((size_t)HID*HID*2);
  _Float16* w2l  = (_Float16*)alloc((size_t)HID*HID*2);
  _Float16* wOh  = (_Float16*)alloc((size_t)OUT_F*HID*2);
  _Float16* wOl  = (_Float16*)alloc((size_t)OUT_F*HID*2);
  (void)ws_size; (void)in_sizes; (void)n_in; (void)out_size;

  const int* srcIdx = ei;        // edge_index[0]
  const int* dstIdx = ei + EE;   // edge_index[1]

  // weight pre-splits + misc zeroing (one launch, ordered before k_bin)
  k_wsplit_all<<<288, 256, 0, stream>>>(W_in, whiI, wloI, W1, w1h, w1l, W2, w2h, w2l,
                                        W_out, wOh, wOl, misc);

  // CSR by dst (2 kernels)
  k_bin<<<NCHUNK, 256, 0, stream>>>(srcIdx, dstIdx, bucketCnt, recs);
  k_csr<<<NB, 512, 0, stream>>>(recs, bucketCnt, rp, colsrc);

  const int gblocks = (NN + 127) / 128;    // 782 = 3.05 blocks/CU
  const int ablocks = (NN + 7) / 8;
  // h = x @ W_in + b_in  -> fp16
  k_gemm_in<<<gblocks, 256, 0, stream>>>(x, whiI, wloI, b_in, H, NN);
  // layer 1: g = h @ W1 (+att dots, +amax) -> fp16; fused alpha+gather
  k_gemm_f16<128,128,true,false,1><<<gblocks, 256, 0, stream>>>(
      (const _Float16*)H, w1h, w1l, nullptr, G, as1, ad1, asrc, adst, gk1, NN);
  k_agg2<<<ablocks, 512, 0, stream>>>(G, asrc, adst, rp, colsrc, bias1, gk1, O1);
  // layer 2
  k_gemm_f16<128,128,true,false,1><<<gblocks, 256, 0, stream>>>(
      (const _Float16*)O1, w2h, w2l, nullptr, G, as2, ad2, asrc, adst, gk2, NN);
  k_agg2<<<ablocks, 512, 0, stream>>>(G, asrc, adst, rp, colsrc, bias2, gk2, (__half*)H);
  // out = o2 @ W_out + b_out -> f32
  k_gemm_f16<128,64,false,true,0><<<gblocks, 256, 0, stream>>>(
      (const _Float16*)H, wOh, wOl, b_out, out, nullptr, nullptr, nullptr, nullptr, nullptr, NN);
}

// Round 15
// 286.842 us; speedup vs baseline: 1.1352x; 1.1352x over previous
//
#include <hip/hip_runtime.h>
#include <hip/hip_fp16.h>
#include <math.h>

// Problem constants
#define NN 100000
#define EE 1600000
constexpr int IN_F = 256, HID = 128, OUT_F = 64;

// CSR bucket-sort geometry
#define NB 196
#define CAP 16384
#define CH 4096
#define NCHUNK 391

typedef __bf16    bf16x8 __attribute__((ext_vector_type(8)));
typedef _Float16  h16x8  __attribute__((ext_vector_type(8)));
typedef float     f32x4  __attribute__((ext_vector_type(4)));

__device__ __forceinline__ f32x4 mfma16b(bf16x8 a, bf16x8 b, f32x4 c){
  return __builtin_amdgcn_mfma_f32_16x16x32_bf16(a, b, c, 0, 0, 0);
}
__device__ __forceinline__ f32x4 mfma16h(h16x8 a, h16x8 b, f32x4 c){
  return __builtin_amdgcn_mfma_f32_16x16x32_f16(a, b, c, 0, 0, 0);
}

// f16 (lo/hi of g2) * f32 alpha + f32 acc (VOP3P mix, exact f32 accumulate)
__device__ __forceinline__ void fmamix2(float& aLo, float& aHi, __half2 g2, float al){
  asm("v_fma_mix_f32 %0, %2, %3, %0 op_sel:[0,0,0] op_sel_hi:[1,0,0]\n\t"
      "v_fma_mix_f32 %1, %2, %3, %1 op_sel:[1,0,0] op_sel_hi:[1,0,0]"
      : "+v"(aLo), "+v"(aHi) : "v"(g2), "v"(al));
}

__device__ __forceinline__ float wred_max(float v){
#pragma unroll
  for (int m=1; m<64; m<<=1) v = fmaxf(v, __shfl_xor(v, m, 64));
  return v;
}
__device__ __forceinline__ float wred_sum(float v){
#pragma unroll
  for (int m=1; m<64; m<<=1) v += __shfl_xor(v, m, 64);
  return v;
}

__device__ __forceinline__ unsigned fkey(float x){
  unsigned u = __float_as_uint(x);
  return (u & 0x80000000u) ? ~u : (u ^ 0x80000000u);
}
__device__ __forceinline__ float funkey(unsigned k){
  return __uint_as_float((k & 0x80000000u) ? (k ^ 0x80000000u) : ~k);
}

// ---------------- CSR build, pass 1 (single dst read: staged in registers) ----------------
__global__ __launch_bounds__(256) void k_bin(const int* __restrict__ src,
    const int* __restrict__ dst, int* __restrict__ bucketCnt, int* __restrict__ recs)
{
  __shared__ int cnt[NB];
  __shared__ int base[NB];
  const int tid = threadIdx.x;
  const int e0 = blockIdx.x * CH;
  const int ne = min(CH, EE - e0);

  for (int i=tid; i<NB; i+=256) cnt[i] = 0;
  __syncthreads();
  int d[16];
#pragma unroll
  for (int q=0; q<16; q++){
    int i = tid + q*256;
    d[q] = (i < ne) ? dst[e0+i] : -1;
    if (d[q] >= 0) atomicAdd(&cnt[d[q]>>9], 1);
  }
  __syncthreads();
  for (int i=tid; i<NB; i+=256) base[i] = atomicAdd(&bucketCnt[i], cnt[i]);
  __syncthreads();
  for (int i=tid; i<NB; i+=256) cnt[i] = 0;
  __syncthreads();
#pragma unroll
  for (int q=0; q<16; q++){
    int i = tid + q*256;
    if (d[q] >= 0){
      int b = d[q] >> 9;
      int r = atomicAdd(&cnt[b], 1);
      int pos = base[b] + r;
      if (pos < CAP) recs[(size_t)b*CAP + pos] = src[e0+i] | ((d[q] & 511) << 17);
    }
  }
}

// ---------------- CSR build, pass 2 (inline bucket prefix) ----------------
__global__ __launch_bounds__(512) void k_csr(const int* __restrict__ recs,
    const int* __restrict__ bucketCnt, int* __restrict__ rp, int* __restrict__ colsrc)
{
  __shared__ int scnt[NB];
  __shared__ int hist[513];
  __shared__ int srcbuf[CAP];
  __shared__ int bs_sh;
  const int tid = threadIdx.x;
  const int b = blockIdx.x;
  for (int i=tid; i<NB; i+=512) scnt[i] = min(bucketCnt[i], CAP);
  if (tid < 513) hist[tid] = 0;
  if (tid == 0) hist[512] = 0;
  __syncthreads();
  if (tid == 0){
    int acc = 0;
    for (int i=0; i<b; i++) acc += scnt[i];
    bs_sh = acc;
  }
  __syncthreads();
  const int bstart = bs_sh;
  const int cntb = scnt[b];
  const int n0 = b << 9;
  const int nnode = min(512, NN - n0);
  const int* rb = recs + (size_t)b*CAP;

  for (int i=tid; i<cntb; i+=512) atomicAdd(&hist[(rb[i] >> 17) + 1], 1);
  __syncthreads();
#pragma unroll
  for (int off=1; off<513; off<<=1){
    int v0 = (tid >= off) ? hist[tid-off] : 0;
    int i1 = tid + 512;
    int v1 = (i1 < 513 && i1 >= off) ? hist[i1-off] : 0;
    __syncthreads();
    hist[tid] += v0;
    if (i1 < 513) hist[i1] += v1;
    __syncthreads();
  }
  for (int l=tid; l<nnode; l+=512) rp[n0+l] = bstart + hist[l];
  if (b == 0 && tid == 0) rp[NN] = EE;
  __syncthreads();
  for (int i=tid; i<cntb; i+=512){
    int rec = rb[i];
    int r = atomicAdd(&hist[rec >> 17], 1);
    srcbuf[r] = rec & 0x1FFFF;
  }
  __syncthreads();
  for (int i=tid; i<cntb; i+=512) colsrc[bstart + i] = srcbuf[i];
}

// ---------------- fused weight pre-split + misc zeroing (one launch) ----------------
__global__ void k_wsplit_all(
    const float* __restrict__ W_in, __bf16* __restrict__ whiI, __bf16* __restrict__ wloI,
    const float* __restrict__ W1, _Float16* __restrict__ w1h, _Float16* __restrict__ w1l,
    const float* __restrict__ W2, _Float16* __restrict__ w2h, _Float16* __restrict__ w2l,
    const float* __restrict__ W_out, _Float16* __restrict__ wOh, _Float16* __restrict__ wOl,
    int* __restrict__ misc)
{
  int idx = blockIdx.x*256 + threadIdx.x;
  if (idx < NB+2) misc[idx] = 0;             // bucketCnt | gk1 | gk2
  if (idx < 32768){                          // W_in [256][128]
    int k = idx >> 7, n = idx & 127;
    float v = W_in[idx];
    __bf16 h = (__bf16)v;
    whiI[n*256 + k] = h;
    wloI[n*256 + k] = (__bf16)(v - (float)h);
  } else if (idx < 49152){                   // W1 [128][128]
    int i = idx - 32768, k = i >> 7, n = i & 127;
    float v = W1[i] * 16.f;
    _Float16 h = (_Float16)v;
    w1h[n*128 + k] = h;
    w1l[n*128 + k] = (_Float16)(v - (float)h);
  } else if (idx < 65536){                   // W2 [128][128]
    int i = idx - 49152, k = i >> 7, n = i & 127;
    float v = W2[i] * 16.f;
    _Float16 h = (_Float16)v;
    w2h[n*128 + k] = h;
    w2l[n*128 + k] = (_Float16)(v - (float)h);
  } else if (idx < 73728){                   // W_out [128][64]
    int i = idx - 65536, k = i / 64, n = i - k*64;
    float v = W_out[i] * 16.f;
    _Float16 h = (_Float16)v;
    wOh[n*128 + k] = h;
    wOl[n*128 + k] = (_Float16)(v - (float)h);
  }
}

// ---------------- GEMM1: H = x @ W_in + b_in  (f32 A -> bf16 split; fp16 out) ----------------
// r13 known-best geometry: 256-row tiles, (256,2). 96 MFMA : 24 ds_read per wave
// per K-chunk — MFMA-dominant. (256,3) spills (r11); 128-tile is LDS-bound (r14).
__global__ __launch_bounds__(256, 2) void k_gemm_in(
    const float* __restrict__ A, const __bf16* __restrict__ Bhi, const __bf16* __restrict__ Blo,
    const float* __restrict__ bias, __half* __restrict__ C, int nrows)
{
  constexpr int K = 256, BN = 128, NF = 8;
  __shared__ __bf16 Ah[256][36];   // 72B stride (known-good)
  __shared__ __bf16 Al[256][36];
  __shared__ __bf16 Bh[BN][36];
  __shared__ __bf16 Bl[BN][36];
  const int tid = threadIdx.x, w = tid >> 6, lane = tid & 63;
  const int lr = lane & 15, lk = (lane >> 4) * 8;
  const int rowBase = blockIdx.x * 256;

  f32x4 acc[4][NF];
#pragma unroll
  for (int f=0; f<4; f++)
#pragma unroll
    for (int nf=0; nf<NF; nf++) acc[f][nf] = (f32x4)(0.f);

  const int bn = tid >> 1, bo = (tid & 1) * 16;

  for (int kc=0; kc<K; kc+=32){
    float4 av[8];
#pragma unroll
    for (int k8=0; k8<8; k8++){
      int P = tid + 256*k8;
      int r = P >> 3, pc = P & 7;
      int gr = rowBase + r; if (gr >= nrows) gr = nrows - 1;
      av[k8] = *(const float4*)(A + (size_t)gr*K + kc + pc*4);
    }
    bf16x8 bh0, bh1, bl0, bl1;
    {
      const __bf16* ph = Bhi + (size_t)bn*K + kc + bo;
      const __bf16* pl = Blo + (size_t)bn*K + kc + bo;
      bh0 = *(const bf16x8*)(ph);  bh1 = *(const bf16x8*)(ph + 8);
      bl0 = *(const bf16x8*)(pl);  bl1 = *(const bf16x8*)(pl + 8);
    }
    __syncthreads();
#pragma unroll
    for (int k8=0; k8<8; k8++){
      int P = tid + 256*k8;
      int r = P >> 3, pc = P & 7;
      float fv[4] = {av[k8].x, av[k8].y, av[k8].z, av[k8].w};
      __bf16 h4[4], l4[4];
#pragma unroll
      for (int u=0; u<4; u++){
        __bf16 h = (__bf16)fv[u];
        h4[u] = h; l4[u] = (__bf16)(fv[u] - (float)h);
      }
      *(uint2*)&Ah[r][pc*4] = *(uint2*)h4;
      *(uint2*)&Al[r][pc*4] = *(uint2*)l4;
    }
    *(bf16x8*)&Bh[bn][bo]     = bh0;  *(bf16x8*)&Bh[bn][bo + 8] = bh1;
    *(bf16x8*)&Bl[bn][bo]     = bl0;  *(bf16x8*)&Bl[bn][bo + 8] = bl1;
    __syncthreads();

    bf16x8 fah[4], fal[4];
#pragma unroll
    for (int f=0; f<4; f++){
      fah[f] = *(const bf16x8*)&Ah[w*64 + f*16 + lr][lk];
      fal[f] = *(const bf16x8*)&Al[w*64 + f*16 + lr][lk];
    }
#pragma unroll
    for (int nf=0; nf<NF; nf++){
      bf16x8 bh = *(const bf16x8*)&Bh[nf*16 + lr][lk];
#pragma unroll
      for (int f=0; f<4; f++) acc[f][nf] = mfma16b(fah[f], bh, acc[f][nf]);
#pragma unroll
      for (int f=0; f<4; f++) acc[f][nf] = mfma16b(fal[f], bh, acc[f][nf]);
      bf16x8 bl = *(const bf16x8*)&Bl[nf*16 + lr][lk];
#pragma unroll
      for (int f=0; f<4; f++) acc[f][nf] = mfma16b(fah[f], bl, acc[f][nf]);
    }
  }

  const int rq = lane >> 4;
#pragma unroll
  for (int f=0; f<4; f++){
    const int rbase = rowBase + w*64 + f*16 + rq*4;
#pragma unroll
    for (int i=0; i<4; i++){
      int row = rbase + i;
      if (row < nrows){
#pragma unroll
        for (int nf=0; nf<NF; nf++){
          float v = acc[f][nf][i] + bias[nf*16 + lr];
          C[(size_t)row*BN + nf*16 + lr] = __float2half(v);
        }
      }
    }
  }
}

// ---------------- f16 GEMM, BK=32, 256-row tiles (r13 known-best) ----------------
template<int K, int BN, bool ATT, bool BIAS, int OMODE>
__global__ __launch_bounds__(256, 2) void k_gemm_f16(
    const _Float16* __restrict__ A, const _Float16* __restrict__ Whi,
    const _Float16* __restrict__ Wlo, const float* __restrict__ bias,
    void* __restrict__ C0, const float* __restrict__ attS, const float* __restrict__ attD,
    float* __restrict__ asrc, float* __restrict__ adst,
    unsigned* __restrict__ gk, int nrows)
{
  constexpr int NF = BN/16;
  __shared__ _Float16 Ah[256][40];   // 80B stride: <=2-way (free)
  __shared__ _Float16 Bh[BN][40];
  __shared__ _Float16 Bl[BN][40];
  const int tid = threadIdx.x, w = tid >> 6, lane = tid & 63;
  const int lr = lane & 15, lk = (lane >> 4) * 8;
  const int rowBase = blockIdx.x * 256;

  f32x4 acc[4][NF];
#pragma unroll
  for (int f=0; f<4; f++)
#pragma unroll
    for (int nf=0; nf<NF; nf++) acc[f][nf] = (f32x4)(0.f);

  const bool bact = tid < BN*2;
  const int bn = tid >> 1, bo = (tid & 1) * 16;

  for (int kc=0; kc<K; kc+=32){
    h16x8 av[4];
#pragma unroll
    for (int k4=0; k4<4; k4++){
      int P = tid + 256*k4;
      int r = P >> 2, pc = P & 3;
      int gr = rowBase + r; if (gr >= nrows) gr = nrows - 1;
      av[k4] = *(const h16x8*)(A + (size_t)gr*K + kc + pc*8);
    }
    h16x8 bh0, bh1, bl0, bl1;
    if (bact){
      const _Float16* ph = Whi + (size_t)bn*K + kc + bo;
      const _Float16* pl = Wlo + (size_t)bn*K + kc + bo;
      bh0 = *(const h16x8*)(ph);  bh1 = *(const h16x8*)(ph + 8);
      bl0 = *(const h16x8*)(pl);  bl1 = *(const h16x8*)(pl + 8);
    }
    __syncthreads();
#pragma unroll
    for (int k4=0; k4<4; k4++){
      int P = tid + 256*k4;
      int r = P >> 2, pc = P & 3;
      *(h16x8*)&Ah[r][pc*8] = av[k4];
    }
    if (bact){
      *(h16x8*)&Bh[bn][bo]     = bh0;  *(h16x8*)&Bh[bn][bo + 8] = bh1;
      *(h16x8*)&Bl[bn][bo]     = bl0;  *(h16x8*)&Bl[bn][bo + 8] = bl1;
    }
    __syncthreads();

    h16x8 fah[4];
#pragma unroll
    for (int f=0; f<4; f++) fah[f] = *(const h16x8*)&Ah[w*64 + f*16 + lr][lk];
#pragma unroll
    for (int nf=0; nf<NF; nf++){
      h16x8 bh = *(const h16x8*)&Bh[nf*16 + lr][lk];
#pragma unroll
      for (int f=0; f<4; f++) acc[f][nf] = mfma16h(fah[f], bh, acc[f][nf]);
      h16x8 bl = *(const h16x8*)&Bl[nf*16 + lr][lk];
#pragma unroll
      for (int f=0; f<4; f++) acc[f][nf] = mfma16h(fah[f], bl, acc[f][nf]);
    }
  }
  // undo the x16 weight scale
#pragma unroll
  for (int f=0; f<4; f++)
#pragma unroll
    for (int nf=0; nf<NF; nf++) acc[f][nf] *= 0.0625f;

  const int rq = lane >> 4;
  float pmax = -3e38f;
#pragma unroll
  for (int f=0; f<4; f++){
    const int rbase = rowBase + w*64 + f*16 + rq*4;
    if (ATT){
      float ps[4] = {0.f,0.f,0.f,0.f}, pd[4] = {0.f,0.f,0.f,0.f};
#pragma unroll
      for (int nf=0; nf<NF; nf++){
        float sv = attS[nf*16 + lr], dv = attD[nf*16 + lr];
#pragma unroll
        for (int i=0;i<4;i++){
          ps[i] = fmaf(acc[f][nf][i], sv, ps[i]);
          pd[i] = fmaf(acc[f][nf][i], dv, pd[i]);
        }
      }
#pragma unroll
      for (int mm=1; mm<16; mm<<=1){
#pragma unroll
        for (int i=0;i<4;i++){
          ps[i] += __shfl_xor(ps[i], mm, 64);
          pd[i] += __shfl_xor(pd[i], mm, 64);
        }
      }
      if (lr == 0){
#pragma unroll
        for (int i=0;i<4;i++){
          int row = rbase + i;
          if (row < nrows){ asrc[row] = ps[i]; adst[row] = pd[i]; }
        }
        pmax = fmaxf(pmax, fmaxf(fmaxf(ps[0],ps[1]), fmaxf(ps[2],ps[3])));
      }
    }
#pragma unroll
    for (int i=0;i<4;i++){
      int row = rbase + i;
      if (row < nrows){
#pragma unroll
        for (int nf=0; nf<NF; nf++){
          float v = acc[f][nf][i] + (BIAS ? bias[nf*16 + lr] : 0.f);
          size_t cidx = (size_t)row*BN + nf*16 + lr;
          if constexpr (OMODE == 0) ((float*)C0)[cidx] = v;
          else                      ((__half*)C0)[cidx] = __float2half(v);
        }
      }
    }
  }
  if (ATT){
    pmax = wred_max(pmax);
    if (lane == 0) atomicMax(gk, fkey(pmax));
  }
}

// ---------------- fused GAT aggregation (unchanged from r13) ----------------
__global__ __launch_bounds__(512) void k_agg2(const __half* __restrict__ g,
    const float* __restrict__ asrc, const float* __restrict__ adst,
    const int* __restrict__ rp, const int* __restrict__ cs,
    const float* __restrict__ bias, const unsigned* __restrict__ gkey,
    __half* __restrict__ out)
{
  __shared__ int2 ebuf[8][128];
  int w = threadIdx.x >> 6, lane = threadIdx.x & 63;
  int node = blockIdx.x*8 + w;
  if (node >= NN) return;
  int r0 = rp[node], deg = rp[node+1] - r0;
  float ad = adst[node];
  float tC = funkey(*gkey) + ad;
  float C = (tC > 0.f) ? tC : 0.2f*tC;
  const int eg = lane >> 4, cl = lane & 15;
  const __half* gcl = g + cl*8;
  const int2* eb = &ebuf[w][eg];

  float ssum = 0.f;
  float a[8] = {0.f,0.f,0.f,0.f,0.f,0.f,0.f,0.f};

  for (int base = 0; base < deg; base += 128){
    int cnt = min(deg - base, 128);
    int cpad = (cnt + 3) & ~3;
    for (int i = lane; i < cpad; i += 64){
      int s = 0; float p = 0.f;
      if (i < cnt){
        s = cs[r0 + base + i];
        float t = asrc[s] + ad;
        float e = (t > 0.f) ? t : 0.2f*t;
        p = __expf(e - C);
        ssum += p;
      }
      ebuf[w][i] = make_int2(s, __float_as_int(p));
    }
    int nst = cpad >> 2;
    int2 e0 = eb[0];
    int2 e1 = (1 < nst) ? eb[4]  : make_int2(0,0);
    int2 e2 = (2 < nst) ? eb[8]  : make_int2(0,0);
    int2 e3 = (3 < nst) ? eb[12] : make_int2(0,0);
    float4 g0 = *(const float4*)(gcl + ((size_t)((unsigned)e0.x << 7)));
    float4 g1 = *(const float4*)(gcl + ((size_t)((unsigned)e1.x << 7)));
    float4 g2 = *(const float4*)(gcl + ((size_t)((unsigned)e2.x << 7)));
    float4 g3 = *(const float4*)(gcl + ((size_t)((unsigned)e3.x << 7)));

#define GSTEP2(EV, GV, SOFF)                                                 \
    {                                                                        \
      float al = __int_as_float(EV.y); float4 cur = GV;                      \
      int nj = j + 4 + SOFF;                                                 \
      if (nj < nst){                                                         \
        EV = eb[4*nj];                                                       \
        GV = *(const float4*)(gcl + ((size_t)((unsigned)EV.x << 7)));        \
      }                                                                      \
      const __half2* hp = (const __half2*)&cur;                              \
      fmamix2(a[0], a[1], hp[0], al);                                        \
      fmamix2(a[2], a[3], hp[1], al);                                        \
      fmamix2(a[4], a[5], hp[2], al);                                        \
      fmamix2(a[6], a[7], hp[3], al);                                        \
    }

    for (int j = 0; j < nst; j += 4){
      GSTEP2(e0, g0, 0)
      if (j + 1 < nst) GSTEP2(e1, g1, 1)
      if (j + 2 < nst) GSTEP2(e2, g2, 2)
      if (j + 3 < nst) GSTEP2(e3, g3, 3)
    }
#undef GSTEP2
  }

  ssum = wred_sum(ssum);
#pragma unroll
  for (int u=0; u<8; u++){
    a[u] += __shfl_xor(a[u], 16, 64);
    a[u] += __shfl_xor(a[u], 32, 64);
  }
  if (eg == 0){
    float inv = 1.f/(ssum + 1e-16f);
    __half hv[8];
#pragma unroll
    for (int u=0; u<8; u++)
      hv[u] = __float2half(fmaxf(a[u]*inv + bias[cl*8 + u], 0.f));
    *(float4*)(out + (size_t)node*HID + cl*8) = *(float4*)hv;
  }
}

// ---------------- host ----------------
extern "C" void kernel_launch(void* const* d_in, const int* in_sizes, int n_in,
                              void* d_out, int out_size, void* d_ws, size_t ws_size,
                              hipStream_t stream) {
  const float* x     = (const float*)d_in[0];
  const int*   ei    = (const int*)  d_in[1];
  const float* W_in  = (const float*)d_in[2];
  const float* b_in  = (const float*)d_in[3];
  const float* W1    = (const float*)d_in[4];
  const float* as1   = (const float*)d_in[5];
  const float* ad1   = (const float*)d_in[6];
  const float* bias1 = (const float*)d_in[7];
  const float* W2    = (const float*)d_in[8];
  const float* as2   = (const float*)d_in[9];
  const float* ad2   = (const float*)d_in[10];
  const float* bias2 = (const float*)d_in[11];
  const float* W_out = (const float*)d_in[12];
  const float* b_out = (const float*)d_in[13];
  float* out = (float*)d_out;

  char* ws = (char*)d_ws;
  size_t off = 0;
  auto alloc = [&](size_t bytes)->void*{ void* p = ws + off; off += (bytes + 255) & ~255ull; return p; };
  __half*   H    = (__half*)  alloc((size_t)NN*HID*2);   // h; later o2
  __half*   G    = (__half*)  alloc((size_t)NN*HID*2);   // g (both layers)
  __half*   O1   = (__half*)  alloc((size_t)NN*HID*2);   // o1
  float*    asrc = (float*)   alloc((size_t)NN*4);
  float*    adst = (float*)   alloc((size_t)NN*4);
  int*      rp   = (int*)     alloc((size_t)(NN+1)*4);
  int*      colsrc = (int*)   alloc((size_t)EE*4);
  int*      recs   = (int*)   alloc((size_t)NB*CAP*4);   // 12.85 MB
  int*      misc   = (int*)   alloc((size_t)(NB+2)*4);   // bucketCnt | gk1 | gk2
  int*      bucketCnt = misc;
  unsigned* gk1 = (unsigned*)(misc + NB);
  unsigned* gk2 = (unsigned*)(misc + NB + 1);
  __bf16*   whiI = (__bf16*) alloc((size_t)HID*IN_F*2);
  __bf16*   wloI = (__bf16*) alloc((size_t)HID*IN_F*2);
  _Float16* w1h  = (_Float16*)alloc((size_t)HID*HID*2);
  _Float16* w1l  = (_Float16*)alloc((size_t)HID*HID*2);
  _Float16* w2h  = (_Float16*)alloc((size_t)HID*HID*2);
  _Float16* w2l  = (_Float16*)alloc((size_t)HID*HID*2);
  _Float16* wOh  = (_Float16*)alloc((size_t)OUT_F*HID*2);
  _Float16* wOl  = (_Float16*)alloc((size_t)OUT_F*HID*2);
  (void)ws_size; (void)in_sizes; (void)n_in; (void)out_size;

  const int* srcIdx = ei;        // edge_index[0]
  const int* dstIdx = ei + EE;   // edge_index[1]

  // weight pre-splits + misc zeroing (one launch, ordered before k_bin)
  k_wsplit_all<<<288, 256, 0, stream>>>(W_in, whiI, wloI, W1, w1h, w1l, W2, w2h, w2l,
                                        W_out, wOh, wOl, misc);

  // CSR by dst (2 kernels)
  k_bin<<<NCHUNK, 256, 0, stream>>>(srcIdx, dstIdx, bucketCnt, recs);
  k_csr<<<NB, 512, 0, stream>>>(recs, bucketCnt, rp, colsrc);

  const int gblocks = (NN + 255) / 256;
  const int ablocks = (NN + 7) / 8;
  // h = x @ W_in + b_in  -> fp16
  k_gemm_in<<<gblocks, 256, 0, stream>>>(x, whiI, wloI, b_in, H, NN);
  // layer 1: g = h @ W1 (+att dots, +amax) -> fp16; fused alpha+gather
  k_gemm_f16<128,128,true,false,1><<<gblocks, 256, 0, stream>>>(
      (const _Float16*)H, w1h, w1l, nullptr, G, as1, ad1, asrc, adst, gk1, NN);
  k_agg2<<<ablocks, 512, 0, stream>>>(G, asrc, adst, rp, colsrc, bias1, gk1, O1);
  // layer 2
  k_gemm_f16<128,128,true,false,1><<<gblocks, 256, 0, stream>>>(
      (const _Float16*)O1, w2h, w2l, nullptr, G, as2, ad2, asrc, adst, gk2, NN);
  k_agg2<<<ablocks, 512, 0, stream>>>(G, asrc, adst, rp, colsrc, bias2, gk2, (__half*)H);
  // out = o2 @ W_out + b_out -> f32
  k_gemm_f16<128,64,false,true,0><<<gblocks, 256, 0, stream>>>(
      (const _Float16*)H, wOh, wOl, b_out, out, nullptr, nullptr, nullptr, nullptr, nullptr, NN);
}